// Round 10
// baseline (283.820 us; speedup 1.0000x reference)
//
#include <hip/hip_runtime.h>
#include <hip/hip_bf16.h>

// PosteriorRotationN: B=8,T=120,N=24,D=48,C=1128,DE=256
// k0w: Wkv f32 -> bf16
// k1 : kv GEMM (bf16 MFMA, swapped operands, bn-grid) -> kvb[bn][c][64]
// k2 : per (bn, 48-t tile): phase A sp MFMA -> g -> padded triangle rows G[t][P_i+j];
//      phase B vectorized row-walk: dx[e] += x_i*row_i[e] (16-wide), dx[i] -= dot(x,row_i)

constexpr int Bc = 8, Tc = 120, Nc = 24, Dc = 48, Cc = 1128, DEc = 256;
constexpr int BNc = Bc * Nc;        // 192
constexpr int KVP = 64;             // kv row padded to 64 (zeros at 48..63)

using short8  = __attribute__((ext_vector_type(8))) short;
using short4v = __attribute__((ext_vector_type(4))) short;
using f32x4   = __attribute__((ext_vector_type(4))) float;

__device__ __forceinline__ ushort f2b(float f) {
    union { float f; unsigned u; } v; v.f = f;
    unsigned r = (v.u + 0x7fffu + ((v.u >> 16) & 1u)) >> 16;
    return (ushort)r;
}
__device__ __forceinline__ float b2f(ushort u) {
    union { unsigned q; float f; } cv; cv.q = ((unsigned)u) << 16; return cv.f;
}
__device__ __forceinline__ short bcast(float f) {
    return (short)__bfloat16_as_ushort(__float2bfloat16(f));
}
__device__ __forceinline__ short8 pack8(const float4& a, const float4& b) {
    short8 r;
    r[0] = bcast(a.x); r[1] = bcast(a.y); r[2] = bcast(a.z); r[3] = bcast(a.w);
    r[4] = bcast(b.x); r[5] = bcast(b.y); r[6] = bcast(b.z); r[7] = bcast(b.w);
    return r;
}
// padded triangle row start (elems): rows 1..16 len16, 17..32 len32, 33..47 len48
__device__ __host__ constexpr int Poff(int i) {
    return i <= 16 ? 16 * (i - 1) : (i <= 32 ? 256 + 32 * (i - 17) : 768 + 48 * (i - 33));
}

// ---------------- K0w: Wkv f32 -> bf16 ----------------
__global__ void k0w(const float* __restrict__ Wkv, ushort* __restrict__ wkvb) {
    int i = blockIdx.x * 256 + threadIdx.x;
    float4 w = *reinterpret_cast<const float4*>(Wkv + i * 4);
    ushort4 u;
    u.x = (ushort)bcast(w.x); u.y = (ushort)bcast(w.y);
    u.z = (ushort)bcast(w.z); u.w = (ushort)bcast(w.w);
    *reinterpret_cast<ushort4*>(wkvb + i * 4) = u;
}

// ---------------- K1: kv GEMM, bf16 MFMA, swapped operands (best-measured) ----------------
constexpr int SWs = 264;  // Wkv LDS stride (bf16 elems)
__global__ __launch_bounds__(256) void k1_kv(const float* __restrict__ ctx,
                                             const ushort* __restrict__ wkvb,
                                             const float* __restrict__ bkv,
                                             ushort* __restrict__ kvb) {
    __shared__ ushort sW[Dc * SWs];          // 25344 B
    const int bn = blockIdx.x, c0 = blockIdx.y * 128;
    const int b = bn / Nc, n = bn % Nc;
    const int tid = threadIdx.x, wave = tid >> 6, lane = tid & 63;
    const int tr = lane & 15, kg = lane >> 4;
    const float* ctxb = ctx + ((size_t)b * Cc * Nc + n) * DEc;

    for (int l = tid; l < Dc * 32; l += 256) {
        int d = l >> 5, e = (l & 31) << 3;
        *reinterpret_cast<short8*>(&sW[d * SWs + e]) =
            *reinterpret_cast<const short8*>(&wkvb[d * DEc + e]);
    }

    const float* crow[2];
    #pragma unroll
    for (int cn = 0; cn < 2; ++cn) {
        int c = c0 + wave * 32 + cn * 16 + tr;
        crow[cn] = ctxb + (size_t)(c < Cc ? c : Cc - 1) * (Nc * DEc);
    }

    f32x4 acc[3][2];
    #pragma unroll
    for (int mf = 0; mf < 3; ++mf)
        #pragma unroll
        for (int cn = 0; cn < 2; ++cn) acc[mf][cn] = (f32x4){0.f, 0.f, 0.f, 0.f};

    __syncthreads();

    #pragma unroll
    for (int ks = 0; ks < 8; ++ks) {
        const int e0 = ks * 32 + kg * 8;
        short8 bfrag[2];
        #pragma unroll
        for (int cn = 0; cn < 2; ++cn) {
            float4 a0 = *reinterpret_cast<const float4*>(crow[cn] + e0);
            float4 a1 = *reinterpret_cast<const float4*>(crow[cn] + e0 + 4);
            bfrag[cn] = pack8(a0, a1);
        }
        short8 afrag[3];
        #pragma unroll
        for (int mf = 0; mf < 3; ++mf)
            afrag[mf] = *reinterpret_cast<const short8*>(&sW[(mf * 16 + tr) * SWs + e0]);
        #pragma unroll
        for (int mf = 0; mf < 3; ++mf)
            #pragma unroll
            for (int cn = 0; cn < 2; ++cn)
                acc[mf][cn] = __builtin_amdgcn_mfma_f32_16x16x32_bf16(afrag[mf], bfrag[cn], acc[mf][cn], 0, 0, 0);
    }

    float4 bias[3];
    #pragma unroll
    for (int mf = 0; mf < 3; ++mf)
        bias[mf] = *reinterpret_cast<const float4*>(bkv + mf * 16 + kg * 4);
    #pragma unroll
    for (int cn = 0; cn < 2; ++cn) {
        int c = c0 + wave * 32 + cn * 16 + tr;
        if (c < Cc) {
            ushort* dst = kvb + ((size_t)bn * Cc + c) * KVP;
            #pragma unroll
            for (int mf = 0; mf < 3; ++mf) {
                ushort4 u;
                u.x = f2b(acc[mf][cn][0] + bias[mf].x);
                u.y = f2b(acc[mf][cn][1] + bias[mf].y);
                u.z = f2b(acc[mf][cn][2] + bias[mf].z);
                u.w = f2b(acc[mf][cn][3] + bias[mf].w);
                *reinterpret_cast<ushort4*>(dst + mf * 16 + kg * 4) = u;
            }
        }
    }
    {
        int row = lane >> 1, half = lane & 1;
        int c = c0 + wave * 32 + row;
        if (c < Cc) {
            short8 z = (short8){0, 0, 0, 0, 0, 0, 0, 0};
            *reinterpret_cast<short8*>(&kvb[((size_t)bn * Cc + c) * KVP + 48 + half * 8]) = z;
        }
    }
}

// ---------------- K2: TT=48, padded triangle rows, vectorized phase B ----------------
constexpr int TT3 = 48;
constexpr int SGT = 1532;   // elems per t (3064 B): 16B-mult, dw-stride 766 (mod32=30 -> ~3-way max)

template<int E0>
__device__ __forceinline__ void phaseB_do(const ushort* __restrict__ gt,
                                          const float* __restrict__ xr,
                                          float* __restrict__ orow) {
    float dx[16];
    #pragma unroll
    for (int u = 0; u < 16; ++u) dx[u] = 0.f;
    // col part: rows i > E0 contribute dx[j] += x_i * row_i[j], j in [E0,E0+16)
    #pragma unroll
    for (int i = E0 + 1; i < 48; ++i) {
        const ushort* row = gt + Poff(i) + E0;
        short4v r0 = *reinterpret_cast<const short4v*>(row + 0);
        short4v r1 = *reinterpret_cast<const short4v*>(row + 4);
        short4v r2 = *reinterpret_cast<const short4v*>(row + 8);
        short4v r3 = *reinterpret_cast<const short4v*>(row + 12);
        float xi = xr[i];
        #pragma unroll
        for (int u = 0; u < 4; ++u) {
            dx[u]      = fmaf(xi, b2f((ushort)r0[u]), dx[u]);
            dx[4 + u]  = fmaf(xi, b2f((ushort)r1[u]), dx[4 + u]);
            dx[8 + u]  = fmaf(xi, b2f((ushort)r2[u]), dx[8 + u]);
            dx[12 + u] = fmaf(xi, b2f((ushort)r3[u]), dx[12 + u]);
        }
    }
    // row part: i in [E0,E0+16): dx[i] -= dot(x[0:i], row_i)  (padding zeros cover j>=i)
    #pragma unroll
    for (int i = (E0 == 0 ? 1 : E0); i < (E0 + 16 < 48 ? E0 + 16 : 48); ++i) {
        float a = 0.f;
        #pragma unroll
        for (int blk = 0; blk < (i + 15) / 16; ++blk) {
            const ushort* row = gt + Poff(i) + blk * 16;
            short4v r0 = *reinterpret_cast<const short4v*>(row + 0);
            short4v r1 = *reinterpret_cast<const short4v*>(row + 4);
            short4v r2 = *reinterpret_cast<const short4v*>(row + 8);
            short4v r3 = *reinterpret_cast<const short4v*>(row + 12);
            #pragma unroll
            for (int u = 0; u < 4; ++u) {
                a = fmaf(xr[blk * 16 + u],      b2f((ushort)r0[u]), a);
                a = fmaf(xr[blk * 16 + 4 + u],  b2f((ushort)r1[u]), a);
                a = fmaf(xr[blk * 16 + 8 + u],  b2f((ushort)r2[u]), a);
                a = fmaf(xr[blk * 16 + 12 + u], b2f((ushort)r3[u]), a);
            }
        }
        dx[i - E0] -= a;
    }
    if (orow) {
        #pragma unroll
        for (int q = 0; q < 4; ++q) {
            float4 v;
            v.x = xr[E0 + q * 4 + 0] + dx[q * 4 + 0];
            v.y = xr[E0 + q * 4 + 1] + dx[q * 4 + 1];
            v.z = xr[E0 + q * 4 + 2] + dx[q * 4 + 2];
            v.w = xr[E0 + q * 4 + 3] + dx[q * 4 + 3];
            *reinterpret_cast<float4*>(orow + E0 + q * 4) = v;
        }
    }
}

// grid 576 = 192 bn x 3 t-tiles(48). XCD-grouped: slot=L%8 -> bn block.
__global__ __launch_bounds__(192) void k2_fused(const float* __restrict__ x,
                                                const ushort* __restrict__ kvb,
                                                float* __restrict__ out) {
    __shared__ __align__(16) ushort sG[TT3 * SGT];   // 147072 B
    __shared__ float sXf[TT3 * 52];                  // 9984 B  (157056 total, 1 block/CU)
    const int L = blockIdx.x;
    const int slot = L & 7, idx = L >> 3;
    const int bn = slot * 24 + idx / 3;
    const int tt = idx % 3;
    const int b = bn / Nc, n = bn % Nc, t0 = tt * TT3;
    const int tid = threadIdx.x, wave = tid >> 6, lane = tid & 63;
    const int tr = lane & 15, kg = lane >> 4;

    // zero G (padding slots must be 0; 73536 elems = 9192 short8)
    for (int l = tid; l < TT3 * SGT / 8; l += 192)
        *reinterpret_cast<short8*>(&sG[l * 8]) = (short8){0, 0, 0, 0, 0, 0, 0, 0};
    // stage x rows f32 (clamped tail)
    for (int l = tid; l < TT3 * 12; l += 192) {
        int t = l / 12, dv = (l % 12) * 4;
        int tg = t0 + t; if (tg > Tc - 1) tg = Tc - 1;
        float4 v = *reinterpret_cast<const float4*>(x + (((size_t)b * Tc + tg) * Nc + n) * Dc + dv);
        *reinterpret_cast<float4*>(&sXf[t * 52 + dv]) = v;
    }
    // A-frags (x) direct from global, bf16-packed
    short8 af[3][2];
    #pragma unroll
    for (int tf = 0; tf < 3; ++tf) {
        int tg = t0 + tf * 16 + tr; if (tg > Tc - 1) tg = Tc - 1;
        const float* xrow = x + (((size_t)b * Tc + tg) * Nc + n) * Dc;
        float4 a0 = *reinterpret_cast<const float4*>(xrow + kg * 8);
        float4 a1 = *reinterpret_cast<const float4*>(xrow + kg * 8 + 4);
        af[tf][0] = pack8(a0, a1);
        if (kg < 2) {
            float4 c0v = *reinterpret_cast<const float4*>(xrow + 32 + kg * 8);
            float4 c1v = *reinterpret_cast<const float4*>(xrow + 32 + kg * 8 + 4);
            af[tf][1] = pack8(c0v, c1v);
        } else af[tf][1] = (short8){0, 0, 0, 0, 0, 0, 0, 0};
    }
    __syncthreads();

    // phase A: 72 c-frags over 3 waves (24 iters), 1-deep prefetch, 6 MFMA/iter
    const ushort* kvbn = kvb + (size_t)bn * Cc * KVP;
    short8 b0, b1, p0, p1;
    {
        int c = wave * 16 + tr;
        const ushort* p = kvbn + (size_t)c * KVP + kg * 8;
        b0 = *reinterpret_cast<const short8*>(p);
        b1 = *reinterpret_cast<const short8*>(p + 32);
    }
    #pragma unroll
    for (int u = 0; u < 24; ++u) {
        if (u < 23) {
            int c = (wave + (u + 1) * 3) * 16 + tr; if (c > Cc - 1) c = Cc - 1;
            const ushort* p = kvbn + (size_t)c * KVP + kg * 8;
            p0 = *reinterpret_cast<const short8*>(p);
            p1 = *reinterpret_cast<const short8*>(p + 32);
        }
        f32x4 a0 = (f32x4){0.f, 0.f, 0.f, 0.f};
        f32x4 a1 = (f32x4){0.f, 0.f, 0.f, 0.f};
        f32x4 a2 = (f32x4){0.f, 0.f, 0.f, 0.f};
        a0 = __builtin_amdgcn_mfma_f32_16x16x32_bf16(af[0][0], b0, a0, 0, 0, 0);
        a0 = __builtin_amdgcn_mfma_f32_16x16x32_bf16(af[0][1], b1, a0, 0, 0, 0);
        a1 = __builtin_amdgcn_mfma_f32_16x16x32_bf16(af[1][0], b0, a1, 0, 0, 0);
        a1 = __builtin_amdgcn_mfma_f32_16x16x32_bf16(af[1][1], b1, a1, 0, 0, 0);
        a2 = __builtin_amdgcn_mfma_f32_16x16x32_bf16(af[2][0], b0, a2, 0, 0, 0);
        a2 = __builtin_amdgcn_mfma_f32_16x16x32_bf16(af[2][1], b1, a2, 0, 0, 0);
        int c = (wave + u * 3) * 16 + tr;
        if (c < Cc) {
            int i = (int)((1.0f + sqrtf(1.0f + 8.0f * (float)c)) * 0.5f);
            while (i * (i - 1) / 2 > c) --i;
            while ((i + 1) * i / 2 <= c) ++i;
            int j = c - i * (i - 1) / 2;
            int off = Poff(i) + j;
            #pragma unroll
            for (int r = 0; r < 4; ++r) {
                int tb = kg * 4 + r;
                float g0 = 0.1f - 0.2f * __builtin_amdgcn_rcpf(__expf(2.0f * a0[r]) + 1.0f);
                float g1 = 0.1f - 0.2f * __builtin_amdgcn_rcpf(__expf(2.0f * a1[r]) + 1.0f);
                float g2 = 0.1f - 0.2f * __builtin_amdgcn_rcpf(__expf(2.0f * a2[r]) + 1.0f);
                sG[tb * SGT + off] = f2b(g0);
                sG[(tb + 16) * SGT + off] = f2b(g1);
                sG[(tb + 32) * SGT + off] = f2b(g2);
            }
        }
        b0 = p0; b1 = p1;
    }
    __syncthreads();

    // phase B: lane = t (0..47), wave = e-range (E0 = 16*wave)
    if (lane < TT3) {
        const int t = lane;
        float xr[48];
        #pragma unroll
        for (int v = 0; v < 12; ++v) {
            float4 w = *reinterpret_cast<const float4*>(&sXf[t * 52 + v * 4]);
            xr[v * 4 + 0] = w.x; xr[v * 4 + 1] = w.y;
            xr[v * 4 + 2] = w.z; xr[v * 4 + 3] = w.w;
        }
        int tg = t0 + t;
        float* orow = (tg < Tc) ? (out + (((size_t)b * Tc + tg) * Nc + n) * Dc) : nullptr;
        const ushort* gt = &sG[t * SGT];
        if (wave == 0)      phaseB_do<0>(gt, xr, orow);
        else if (wave == 1) phaseB_do<16>(gt, xr, orow);
        else                phaseB_do<32>(gt, xr, orow);
    }
}

extern "C" void kernel_launch(void* const* d_in, const int* in_sizes, int n_in,
                              void* d_out, int out_size, void* d_ws, size_t ws_size,
                              hipStream_t stream) {
    (void)in_sizes; (void)n_in; (void)out_size; (void)ws_size;
    const float* x   = (const float*)d_in[0];
    const float* ctx = (const float*)d_in[1];
    const float* Wkv = (const float*)d_in[2];
    const float* bkv = (const float*)d_in[3];
    float* out   = (float*)d_out;
    ushort* wkvb = (ushort*)d_ws;                          // 24 KB
    ushort* kvb  = (ushort*)((char*)d_ws + 32768);         // 27.7 MB

    k0w<<<dim3(12), dim3(256), 0, stream>>>(Wkv, wkvb);
    k1_kv<<<dim3(BNc, 9), dim3(256), 0, stream>>>(ctx, wkvb, bkv, kvb);
    k2_fused<<<dim3(BNc * 3), dim3(192), 0, stream>>>(x, kvb, out);
}

// Round 11
// 112.369 us; speedup vs baseline: 2.5258x; 2.5258x over previous
//
#include <hip/hip_runtime.h>
#include <hip/hip_bf16.h>

// PosteriorRotationN: B=8,T=120,N=24,D=48,C=1128,DE=256
// k0w: Wkv f32 -> bf16 (24 KB, L2-resident)
// k1 : kv GEMM (bf16 MFMA, swapped operands, bn-grid) -> kvb[bn][c][64]   [97.6-µs config]
// k2 : TT=16 t-tile; phase A sp MFMA -> g bf16 in sG[t][c]; phase B register-x gather dot.
//      Thinned for occupancy: 42.1 KB LDS -> 3 blocks/CU (was 78.7 KB / 2).

constexpr int Bc = 8, Tc = 120, Nc = 24, Dc = 48, Cc = 1128, DEc = 256;
constexpr int BNc = Bc * Nc;        // 192
constexpr int KVP = 64;             // kv row padded to 64 (zeros at 48..63)

using short8 = __attribute__((ext_vector_type(8))) short;
using f32x4  = __attribute__((ext_vector_type(4))) float;

__device__ __forceinline__ ushort f2b(float f) {
    union { float f; unsigned u; } v; v.f = f;
    unsigned r = (v.u + 0x7fffu + ((v.u >> 16) & 1u)) >> 16;
    return (ushort)r;
}
__device__ __forceinline__ float b2f(ushort u) {
    union { unsigned q; float f; } cv; cv.q = ((unsigned)u) << 16; return cv.f;
}
__device__ __forceinline__ short bcast(float f) {
    return (short)__bfloat16_as_ushort(__float2bfloat16(f));
}
__device__ __forceinline__ short8 pack8(const float4& a, const float4& b) {
    short8 r;
    r[0] = bcast(a.x); r[1] = bcast(a.y); r[2] = bcast(a.z); r[3] = bcast(a.w);
    r[4] = bcast(b.x); r[5] = bcast(b.y); r[6] = bcast(b.z); r[7] = bcast(b.w);
    return r;
}

// ---------------- K0w: Wkv f32 -> bf16 ----------------
__global__ void k0w(const float* __restrict__ Wkv, ushort* __restrict__ wkvb) {
    int i = blockIdx.x * 256 + threadIdx.x;
    float4 w = *reinterpret_cast<const float4*>(Wkv + i * 4);
    ushort4 u;
    u.x = (ushort)bcast(w.x); u.y = (ushort)bcast(w.y);
    u.z = (ushort)bcast(w.z); u.w = (ushort)bcast(w.w);
    *reinterpret_cast<ushort4*>(wkvb + i * 4) = u;
}

// ---------------- K1: kv GEMM, bf16 MFMA, swapped operands (97.6-µs config) ----------------
constexpr int SWs = 264;  // Wkv LDS stride (bf16 elems)
__global__ __launch_bounds__(256) void k1_kv(const float* __restrict__ ctx,
                                             const ushort* __restrict__ wkvb,
                                             const float* __restrict__ bkv,
                                             ushort* __restrict__ kvb) {
    __shared__ ushort sW[Dc * SWs];          // 25344 B
    const int bn = blockIdx.x, c0 = blockIdx.y * 128;
    const int b = bn / Nc, n = bn % Nc;
    const int tid = threadIdx.x, wave = tid >> 6, lane = tid & 63;
    const int tr = lane & 15, kg = lane >> 4;
    const float* ctxb = ctx + ((size_t)b * Cc * Nc + n) * DEc;

    for (int l = tid; l < Dc * 32; l += 256) {
        int d = l >> 5, e = (l & 31) << 3;
        *reinterpret_cast<short8*>(&sW[d * SWs + e]) =
            *reinterpret_cast<const short8*>(&wkvb[d * DEc + e]);
    }

    const float* crow[2];
    #pragma unroll
    for (int cn = 0; cn < 2; ++cn) {
        int c = c0 + wave * 32 + cn * 16 + tr;
        crow[cn] = ctxb + (size_t)(c < Cc ? c : Cc - 1) * (Nc * DEc);
    }

    f32x4 acc[3][2];
    #pragma unroll
    for (int mf = 0; mf < 3; ++mf)
        #pragma unroll
        for (int cn = 0; cn < 2; ++cn) acc[mf][cn] = (f32x4){0.f, 0.f, 0.f, 0.f};

    __syncthreads();

    #pragma unroll
    for (int ks = 0; ks < 8; ++ks) {
        const int e0 = ks * 32 + kg * 8;
        short8 bfrag[2];
        #pragma unroll
        for (int cn = 0; cn < 2; ++cn) {
            float4 a0 = *reinterpret_cast<const float4*>(crow[cn] + e0);
            float4 a1 = *reinterpret_cast<const float4*>(crow[cn] + e0 + 4);
            bfrag[cn] = pack8(a0, a1);
        }
        short8 afrag[3];
        #pragma unroll
        for (int mf = 0; mf < 3; ++mf)
            afrag[mf] = *reinterpret_cast<const short8*>(&sW[(mf * 16 + tr) * SWs + e0]);
        #pragma unroll
        for (int mf = 0; mf < 3; ++mf)
            #pragma unroll
            for (int cn = 0; cn < 2; ++cn)
                acc[mf][cn] = __builtin_amdgcn_mfma_f32_16x16x32_bf16(afrag[mf], bfrag[cn], acc[mf][cn], 0, 0, 0);
    }

    float4 bias[3];
    #pragma unroll
    for (int mf = 0; mf < 3; ++mf)
        bias[mf] = *reinterpret_cast<const float4*>(bkv + mf * 16 + kg * 4);
    #pragma unroll
    for (int cn = 0; cn < 2; ++cn) {
        int c = c0 + wave * 32 + cn * 16 + tr;
        if (c < Cc) {
            ushort* dst = kvb + ((size_t)bn * Cc + c) * KVP;
            #pragma unroll
            for (int mf = 0; mf < 3; ++mf) {
                ushort4 u;
                u.x = f2b(acc[mf][cn][0] + bias[mf].x);
                u.y = f2b(acc[mf][cn][1] + bias[mf].y);
                u.z = f2b(acc[mf][cn][2] + bias[mf].z);
                u.w = f2b(acc[mf][cn][3] + bias[mf].w);
                *reinterpret_cast<ushort4*>(dst + mf * 16 + kg * 4) = u;
            }
        }
    }
    {
        int row = lane >> 1, half = lane & 1;
        int c = c0 + wave * 32 + row;
        if (c < Cc) {
            short8 z = (short8){0, 0, 0, 0, 0, 0, 0, 0};
            *reinterpret_cast<short8*>(&kvb[((size_t)bn * Cc + c) * KVP + 48 + half * 8]) = z;
        }
    }
}

// ---------------- K2: TT=16, bf16 sG, register-x phase B, 3 blocks/CU ----------------
// grid 1536 = 192 bn x 8 t-tiles(16), XCD-swizzled.
constexpr int SG2 = 1140;  // sG ushort stride: 2280 B row; 16-lane t-read -> banks 26t mod 32, all distinct
__global__ __launch_bounds__(256, 3) void k2_fused(const float* __restrict__ x,
                                                   const ushort* __restrict__ kvb,
                                                   float* __restrict__ out) {
    __shared__ ushort sG[16 * SG2];    // 36480 B (bf16 g)
    __shared__ float  sXf[16 * 52];    // 3328 B
    __shared__ ushort sXb[16 * 72];    // 2304 B (K-padded to 64 w/ zeros) -> 42112 B total
    const int L = blockIdx.x;
    const int bn = (L & 7) + 8 * (L >> 6);   // bn%8 == XCD slot
    const int tt = (L >> 3) & 7;
    const int b = bn / Nc, n = bn % Nc, t0 = tt * 16;
    const int tid = threadIdx.x, wave = tid >> 6, lane = tid & 63;
    const int tr = lane & 15, kg = lane >> 4;

    for (int l = tid; l < 16 * 72 / 4; l += 256)
        *reinterpret_cast<ushort4*>(&sXb[l * 4]) = make_ushort4(0, 0, 0, 0);
    for (int l = tid; l < 16 * 12; l += 256)           // zero pad cols 1128..1139 (d==e reads)
        sG[(l / 12) * SG2 + 1128 + (l % 12)] = 0;
    __syncthreads();
    if (tid < 192) {
        int t = tid / 12, dv = (tid % 12) * 4, tg = t0 + t;
        float4 v = make_float4(0.f, 0.f, 0.f, 0.f);
        if (tg < Tc) v = *reinterpret_cast<const float4*>(x + (((size_t)b * Tc + tg) * Nc + n) * Dc + dv);
        *reinterpret_cast<float4*>(&sXf[t * 52 + dv]) = v;
        *reinterpret_cast<ushort4*>(&sXb[t * 72 + dv]) = make_ushort4(f2b(v.x), f2b(v.y), f2b(v.z), f2b(v.w));
    }
    __syncthreads();
    // A-frags (t=lane&15, k contiguous-8) hoisted to regs
    const short8 af0 = *reinterpret_cast<const short8*>(&sXb[tr * 72 + kg * 8]);
    const short8 af1 = *reinterpret_cast<const short8*>(&sXb[tr * 72 + 32 + kg * 8]);

    // phase A: 72 c-frags (incl. pad) = 9 iters x 4 waves x 2 frags, 1-deep prefetch
    const ushort* kvbn = kvb + (size_t)bn * Cc * KVP;
    short8 cb0[2], cb1[2], nb0[2], nb1[2];
    #pragma unroll
    for (int q = 0; q < 2; ++q) {
        int c = (wave * 2 + q) * 16 + tr;                       // <= 127, in range
        const ushort* p = kvbn + (size_t)c * KVP + kg * 8;
        cb0[q] = *reinterpret_cast<const short8*>(p);
        cb1[q] = *reinterpret_cast<const short8*>(p + 32);
    }
    #pragma unroll
    for (int u = 0; u < 9; ++u) {
        if (u < 8) {
            #pragma unroll
            for (int q = 0; q < 2; ++q) {
                int c = ((u + 1) * 8 + wave * 2 + q) * 16 + tr;
                if (c > Cc - 1) c = Cc - 1;
                const ushort* p = kvbn + (size_t)c * KVP + kg * 8;
                nb0[q] = *reinterpret_cast<const short8*>(p);
                nb1[q] = *reinterpret_cast<const short8*>(p + 32);
            }
        }
        #pragma unroll
        for (int q = 0; q < 2; ++q) {
            f32x4 a = (f32x4){0.f, 0.f, 0.f, 0.f};
            a = __builtin_amdgcn_mfma_f32_16x16x32_bf16(af0, cb0[q], a, 0, 0, 0);
            a = __builtin_amdgcn_mfma_f32_16x16x32_bf16(af1, cb1[q], a, 0, 0, 0);
            int c = (u * 8 + wave * 2 + q) * 16 + tr;
            if (c < Cc) {
                #pragma unroll
                for (int r = 0; r < 4; ++r) {   // D: col=tr (=c), row=kg*4+r (=t)
                    float g = 0.1f - 0.2f * __builtin_amdgcn_rcpf(__expf(2.0f * a[r]) + 1.0f);
                    sG[(kg * 4 + r) * SG2 + c] = f2b(g);
                }
            }
        }
        #pragma unroll
        for (int q = 0; q < 2; ++q) { cb0[q] = nb0[q]; cb1[q] = nb1[q]; }
    }
    __syncthreads();

    // phase B: thread = (t = tid&15, e-triple eg = tid>>4); x row in registers
    const int tb = tid & 15, eg = tid >> 4;
    float xr[48];
    #pragma unroll
    for (int v = 0; v < 12; ++v) {
        float4 w = *reinterpret_cast<const float4*>(&sXf[tb * 52 + v * 4]);
        xr[v * 4 + 0] = w.x; xr[v * 4 + 1] = w.y;
        xr[v * 4 + 2] = w.z; xr[v * 4 + 3] = w.w;
    }
    float dxa[3]; int ep[3], te[3];
    #pragma unroll
    for (int p = 0; p < 3; ++p) {
        ep[p] = eg * 3 + p;
        te[p] = ep[p] * (ep[p] - 1) / 2;
        dxa[p] = 0.f;
    }
    const ushort* grow = &sG[tb * SG2];
    int td = 0;
    #pragma unroll 8
    for (int d = 0; d < 48; ++d) {
        float xv = xr[d];
        #pragma unroll
        for (int p = 0; p < 3; ++p) {
            bool gt = d > ep[p];
            int c = gt ? (td + ep[p]) : (te[p] + d);   // d==e -> c=e(e+1)/2 <= 1128 (zeroed pad)
            float gv = b2f(grow[c]);
            float m = gt ? xv : -xv;
            if (d == ep[p]) m = 0.f;
            dxa[p] = fmaf(m, gv, dxa[p]);
        }
        td += d;
    }
    int tg = t0 + tb;
    if (tg < Tc) {
        #pragma unroll
        for (int p = 0; p < 3; ++p)
            out[(((size_t)b * Tc + tg) * Nc + n) * Dc + ep[p]] = sXf[tb * 52 + ep[p]] + dxa[p];
    }
}

extern "C" void kernel_launch(void* const* d_in, const int* in_sizes, int n_in,
                              void* d_out, int out_size, void* d_ws, size_t ws_size,
                              hipStream_t stream) {
    (void)in_sizes; (void)n_in; (void)out_size; (void)ws_size;
    const float* x   = (const float*)d_in[0];
    const float* ctx = (const float*)d_in[1];
    const float* Wkv = (const float*)d_in[2];
    const float* bkv = (const float*)d_in[3];
    float* out   = (float*)d_out;
    ushort* wkvb = (ushort*)d_ws;                          // 24 KB
    ushort* kvb  = (ushort*)((char*)d_ws + 32768);         // 27.7 MB

    k0w<<<dim3(12), dim3(256), 0, stream>>>(Wkv, wkvb);
    k1_kv<<<dim3(BNc, 9), dim3(256), 0, stream>>>(ctx, wkvb, bkv, kvb);
    k2_fused<<<dim3(BNc * 8), dim3(256), 0, stream>>>(x, kvb, out);
}

// Round 12
// 94.215 us; speedup vs baseline: 3.0125x; 1.1927x over previous
//
#include <hip/hip_runtime.h>
#include <hip/hip_bf16.h>

// PosteriorRotationN: B=8,T=120,N=24,D=48,C=1128,DE=256
// k0w: Wkv f32 -> bf16 (24 KB, L2-resident)
// k1 : kv GEMM (bf16 MFMA, swapped operands, bn-grid) -> kvb[bn][c][64]   [97.6-µs config]
// k2 : TT=16; phase A sp MFMA (1-deep kv prefetch) -> g bf16 -> sG[t][c];
//      phase B R6-structure gather dot (x from LDS, no register arrays). 42.1 KB -> 3 blk/CU.

constexpr int Bc = 8, Tc = 120, Nc = 24, Dc = 48, Cc = 1128, DEc = 256;
constexpr int BNc = Bc * Nc;        // 192
constexpr int KVP = 64;             // kv row padded to 64 (zeros at 48..63)

using short8 = __attribute__((ext_vector_type(8))) short;
using f32x4  = __attribute__((ext_vector_type(4))) float;

__device__ __forceinline__ ushort f2b(float f) {
    union { float f; unsigned u; } v; v.f = f;
    unsigned r = (v.u + 0x7fffu + ((v.u >> 16) & 1u)) >> 16;
    return (ushort)r;
}
__device__ __forceinline__ float b2f(ushort u) {
    union { unsigned q; float f; } cv; cv.q = ((unsigned)u) << 16; return cv.f;
}
__device__ __forceinline__ short bcast(float f) {
    return (short)__bfloat16_as_ushort(__float2bfloat16(f));
}
__device__ __forceinline__ short8 pack8(const float4& a, const float4& b) {
    short8 r;
    r[0] = bcast(a.x); r[1] = bcast(a.y); r[2] = bcast(a.z); r[3] = bcast(a.w);
    r[4] = bcast(b.x); r[5] = bcast(b.y); r[6] = bcast(b.z); r[7] = bcast(b.w);
    return r;
}

// ---------------- K0w: Wkv f32 -> bf16 ----------------
__global__ void k0w(const float* __restrict__ Wkv, ushort* __restrict__ wkvb) {
    int i = blockIdx.x * 256 + threadIdx.x;
    float4 w = *reinterpret_cast<const float4*>(Wkv + i * 4);
    ushort4 u;
    u.x = (ushort)bcast(w.x); u.y = (ushort)bcast(w.y);
    u.z = (ushort)bcast(w.z); u.w = (ushort)bcast(w.w);
    *reinterpret_cast<ushort4*>(wkvb + i * 4) = u;
}

// ---------------- K1: kv GEMM, bf16 MFMA, swapped operands (97.6-µs config) ----------------
constexpr int SWs = 264;  // Wkv LDS stride (bf16 elems)
__global__ __launch_bounds__(256) void k1_kv(const float* __restrict__ ctx,
                                             const ushort* __restrict__ wkvb,
                                             const float* __restrict__ bkv,
                                             ushort* __restrict__ kvb) {
    __shared__ ushort sW[Dc * SWs];          // 25344 B
    const int bn = blockIdx.x, c0 = blockIdx.y * 128;
    const int b = bn / Nc, n = bn % Nc;
    const int tid = threadIdx.x, wave = tid >> 6, lane = tid & 63;
    const int tr = lane & 15, kg = lane >> 4;
    const float* ctxb = ctx + ((size_t)b * Cc * Nc + n) * DEc;

    for (int l = tid; l < Dc * 32; l += 256) {
        int d = l >> 5, e = (l & 31) << 3;
        *reinterpret_cast<short8*>(&sW[d * SWs + e]) =
            *reinterpret_cast<const short8*>(&wkvb[d * DEc + e]);
    }

    const float* crow[2];
    #pragma unroll
    for (int cn = 0; cn < 2; ++cn) {
        int c = c0 + wave * 32 + cn * 16 + tr;
        crow[cn] = ctxb + (size_t)(c < Cc ? c : Cc - 1) * (Nc * DEc);
    }

    f32x4 acc[3][2];
    #pragma unroll
    for (int mf = 0; mf < 3; ++mf)
        #pragma unroll
        for (int cn = 0; cn < 2; ++cn) acc[mf][cn] = (f32x4){0.f, 0.f, 0.f, 0.f};

    __syncthreads();

    #pragma unroll
    for (int ks = 0; ks < 8; ++ks) {
        const int e0 = ks * 32 + kg * 8;
        short8 bfrag[2];
        #pragma unroll
        for (int cn = 0; cn < 2; ++cn) {
            float4 a0 = *reinterpret_cast<const float4*>(crow[cn] + e0);
            float4 a1 = *reinterpret_cast<const float4*>(crow[cn] + e0 + 4);
            bfrag[cn] = pack8(a0, a1);
        }
        short8 afrag[3];
        #pragma unroll
        for (int mf = 0; mf < 3; ++mf)
            afrag[mf] = *reinterpret_cast<const short8*>(&sW[(mf * 16 + tr) * SWs + e0]);
        #pragma unroll
        for (int mf = 0; mf < 3; ++mf)
            #pragma unroll
            for (int cn = 0; cn < 2; ++cn)
                acc[mf][cn] = __builtin_amdgcn_mfma_f32_16x16x32_bf16(afrag[mf], bfrag[cn], acc[mf][cn], 0, 0, 0);
    }

    float4 bias[3];
    #pragma unroll
    for (int mf = 0; mf < 3; ++mf)
        bias[mf] = *reinterpret_cast<const float4*>(bkv + mf * 16 + kg * 4);
    #pragma unroll
    for (int cn = 0; cn < 2; ++cn) {
        int c = c0 + wave * 32 + cn * 16 + tr;
        if (c < Cc) {
            ushort* dst = kvb + ((size_t)bn * Cc + c) * KVP;
            #pragma unroll
            for (int mf = 0; mf < 3; ++mf) {
                ushort4 u;
                u.x = f2b(acc[mf][cn][0] + bias[mf].x);
                u.y = f2b(acc[mf][cn][1] + bias[mf].y);
                u.z = f2b(acc[mf][cn][2] + bias[mf].z);
                u.w = f2b(acc[mf][cn][3] + bias[mf].w);
                *reinterpret_cast<ushort4*>(dst + mf * 16 + kg * 4) = u;
            }
        }
    }
    {
        int row = lane >> 1, half = lane & 1;
        int c = c0 + wave * 32 + row;
        if (c < Cc) {
            short8 z = (short8){0, 0, 0, 0, 0, 0, 0, 0};
            *reinterpret_cast<short8*>(&kvb[((size_t)bn * Cc + c) * KVP + 48 + half * 8]) = z;
        }
    }
}

// ---------------- K2: TT=16, bf16 sG, R6 phase B, prefetched phase A, 3 blk/CU ----------------
// grid 1536 = 192 bn x 8 t-tiles(16), XCD-swizzled (k1 wrote bn's kvb on XCD bn%8; L&7==bn%8).
constexpr int SG2 = 1140;  // ushort stride (2280 B)
__global__ __launch_bounds__(256, 3) void k2_fused(const float* __restrict__ x,
                                                   const ushort* __restrict__ kvb,
                                                   float* __restrict__ out) {
    __shared__ ushort sG[16 * SG2];    // 36480 B (bf16 g)
    __shared__ float  sXf[16 * 52];    // 3328 B
    __shared__ ushort sXb[16 * 72];    // 2304 B -> 42112 B total
    const int L = blockIdx.x;
    const int bn = (L & 7) + 8 * (L >> 6);   // bn%8 == XCD slot
    const int tt = (L >> 3) & 7;
    const int b = bn / Nc, n = bn % Nc, t0 = tt * 16;
    const int tid = threadIdx.x, wave = tid >> 6, lane = tid & 63;
    const int tr = lane & 15, kg = lane >> 4;

    for (int l = tid; l < 16 * 72 / 4; l += 256)
        *reinterpret_cast<ushort4*>(&sXb[l * 4]) = make_ushort4(0, 0, 0, 0);
    for (int l = tid; l < 16 * 12; l += 256)           // zero pad cols 1128..1139 (d==e reads)
        sG[(l / 12) * SG2 + 1128 + (l % 12)] = 0;
    __syncthreads();
    if (tid < 192) {
        int t = tid / 12, dv = (tid % 12) * 4, tg = t0 + t;
        float4 v = make_float4(0.f, 0.f, 0.f, 0.f);
        if (tg < Tc) v = *reinterpret_cast<const float4*>(x + (((size_t)b * Tc + tg) * Nc + n) * Dc + dv);
        *reinterpret_cast<float4*>(&sXf[t * 52 + dv]) = v;
        *reinterpret_cast<ushort4*>(&sXb[t * 72 + dv]) = make_ushort4(f2b(v.x), f2b(v.y), f2b(v.z), f2b(v.w));
    }
    __syncthreads();
    // A-frags (t=lane&15, k contiguous-8) hoisted to regs
    const short8 af0 = *reinterpret_cast<const short8*>(&sXb[tr * 72 + kg * 8]);
    const short8 af1 = *reinterpret_cast<const short8*>(&sXb[tr * 72 + 32 + kg * 8]);

    // phase A: 72 c-frags = 18 iters x 4 waves, 1-deep prefetch
    const ushort* kvbn = kvb + (size_t)bn * Cc * KVP;
    short8 b0, b1, p0, p1;
    {
        int c = wave * 16 + tr;
        const ushort* p = kvbn + (size_t)c * KVP + kg * 8;
        b0 = *reinterpret_cast<const short8*>(p);
        b1 = *reinterpret_cast<const short8*>(p + 32);
    }
    #pragma unroll
    for (int u = 0; u < 18; ++u) {
        if (u < 17) {
            int c = (wave + (u + 1) * 4) * 16 + tr; if (c > Cc - 1) c = Cc - 1;
            const ushort* p = kvbn + (size_t)c * KVP + kg * 8;
            p0 = *reinterpret_cast<const short8*>(p);
            p1 = *reinterpret_cast<const short8*>(p + 32);
        }
        f32x4 a = (f32x4){0.f, 0.f, 0.f, 0.f};
        a = __builtin_amdgcn_mfma_f32_16x16x32_bf16(af0, b0, a, 0, 0, 0);
        a = __builtin_amdgcn_mfma_f32_16x16x32_bf16(af1, b1, a, 0, 0, 0);
        int c = (wave + u * 4) * 16 + tr;
        if (c < Cc) {
            #pragma unroll
            for (int r = 0; r < 4; ++r) {   // D: col=tr (=c), row=kg*4+r (=t)
                float g = 0.1f - 0.2f * __builtin_amdgcn_rcpf(__expf(2.0f * a[r]) + 1.0f);
                sG[(kg * 4 + r) * SG2 + c] = f2b(g);
            }
        }
        b0 = p0; b1 = p1;
    }
    __syncthreads();

    // phase B (R6 structure): thread owns 3 (t,e) pairs; x and g from LDS, no reg arrays
    int ea[3], ta[3], tea[3];
    float dxa[3];
    #pragma unroll
    for (int p = 0; p < 3; ++p) {
        int idx = tid + p * 256;
        ta[p] = idx / 48; ea[p] = idx % 48;
        tea[p] = ea[p] * (ea[p] - 1) / 2;
        dxa[p] = 0.f;
    }
    int td = 0;
    #pragma unroll 4
    for (int d = 0; d < 48; ++d) {
        #pragma unroll
        for (int p = 0; p < 3; ++p) {
            bool gt = d > ea[p];
            int c = gt ? (td + ea[p]) : (tea[p] + d);   // d==e -> c<=1128 (zeroed pad)
            float gv = b2f(sG[ta[p] * SG2 + c]);
            float xv = sXf[ta[p] * 52 + d];
            float m = gt ? xv : -xv;
            if (d == ea[p]) m = 0.f;
            dxa[p] = fmaf(m, gv, dxa[p]);
        }
        td += d;
    }
    #pragma unroll
    for (int p = 0; p < 3; ++p) {
        int tg = t0 + ta[p];
        if (tg < Tc)
            out[(((size_t)b * Tc + tg) * Nc + n) * Dc + ea[p]] = sXf[ta[p] * 52 + ea[p]] + dxa[p];
    }
}

extern "C" void kernel_launch(void* const* d_in, const int* in_sizes, int n_in,
                              void* d_out, int out_size, void* d_ws, size_t ws_size,
                              hipStream_t stream) {
    (void)in_sizes; (void)n_in; (void)out_size; (void)ws_size;
    const float* x   = (const float*)d_in[0];
    const float* ctx = (const float*)d_in[1];
    const float* Wkv = (const float*)d_in[2];
    const float* bkv = (const float*)d_in[3];
    float* out   = (float*)d_out;
    ushort* wkvb = (ushort*)d_ws;                          // 24 KB
    ushort* kvb  = (ushort*)((char*)d_ws + 32768);         // 27.7 MB

    k0w<<<dim3(12), dim3(256), 0, stream>>>(Wkv, wkvb);
    k1_kv<<<dim3(BNc, 9), dim3(256), 0, stream>>>(ctx, wkvb, bkv, kvb);
    k2_fused<<<dim3(BNc * 8), dim3(256), 0, stream>>>(x, kvb, out);
}